// Round 1
// baseline (7190.316 us; speedup 1.0000x reference)
//
#include <hip/hip_runtime.h>
#include <hip/hip_bf16.h>

// LSTM + dot-attention recurrence, B=64, S=512, D_IN=D_HID=1024, STEPS=64.
// Round 0: all-fp32 correctness baseline.
//   per step: gates GEMM (split-K partials) -> cell -> inp GEMM -> fused
//   one-pass attention (online softmax, LDS ctx tiles) -> merge -> out GEMM
//   -> finalize (tanh + output write + h carry).
// No atomics: split-K partials are reduced by the consumer kernel, so every
// ws buffer is fully written before read (0xAA poison safe).

#define B_    64
#define S_    512
#define DHID  1024
#define STEPS 64

__device__ __forceinline__ float sigmf(float x) { return 1.0f / (1.0f + expf(-x)); }

// C_part[kc][64, N] = A[64, Kchunk] @ B[N, Kchunk]^T  (B row-major [N, ldb])
__global__ __launch_bounds__(256) void gemm64_part(
    const float* __restrict__ A, int lda,
    const float* __restrict__ B, int ldb,
    float* __restrict__ Cp, int N, int kchunk) {
  __shared__ __align__(16) float As[64][20];
  __shared__ __align__(16) float Bs[64][20];
  const int tid = threadIdx.x;
  const int tx = tid & 15, ty = tid >> 4;
  const int n0 = blockIdx.x * 64;
  const int kc = blockIdx.y;
  float acc[4][4] = {};
  const int kbeg = kc * kchunk, kend = kbeg + kchunk;
  for (int k0 = kbeg; k0 < kend; k0 += 16) {
    __syncthreads();
#pragma unroll
    for (int p = 0; p < 4; ++p) {
      As[p * 16 + ty][tx] = A[(size_t)(p * 16 + ty) * lda + k0 + tx];
      Bs[p * 16 + ty][tx] = B[(size_t)(n0 + p * 16 + ty) * ldb + k0 + tx];
    }
    __syncthreads();
#pragma unroll
    for (int kk = 0; kk < 16; kk += 4) {
      float4 av[4], bv[4];
#pragma unroll
      for (int i = 0; i < 4; ++i) av[i] = *(const float4*)&As[ty * 4 + i][kk];
#pragma unroll
      for (int j = 0; j < 4; ++j) bv[j] = *(const float4*)&Bs[tx * 4 + j][kk];
#pragma unroll
      for (int i = 0; i < 4; ++i)
#pragma unroll
        for (int j = 0; j < 4; ++j)
          acc[i][j] += av[i].x * bv[j].x + av[i].y * bv[j].y +
                       av[i].z * bv[j].z + av[i].w * bv[j].w;
    }
  }
  float* Cpart = Cp + (size_t)kc * 64 * N;
#pragma unroll
  for (int i = 0; i < 4; ++i)
#pragma unroll
    for (int j = 0; j < 4; ++j)
      Cpart[(size_t)(ty * 4 + i) * N + n0 + tx * 4 + j] = acc[i][j];
}

// gates partial-sum + bias + LSTM cell -> c (in place), hy
__global__ __launch_bounds__(256) void cell_k(
    const float* __restrict__ gatesP, const float* __restrict__ bh,
    float* __restrict__ c, float* __restrict__ hy) {
  int idx = blockIdx.x * 256 + threadIdx.x;  // 64*1024
  int b = idx >> 10, j = idx & 1023;
  float gi = bh[j], gf = bh[1024 + j], gg = bh[2048 + j], go = bh[3072 + j];
#pragma unroll
  for (int p = 0; p < 4; ++p) {
    const float* gp = gatesP + (size_t)p * 64 * 4096 + (size_t)b * 4096;
    gi += gp[j]; gf += gp[1024 + j]; gg += gp[2048 + j]; go += gp[3072 + j];
  }
  float cy = sigmf(gf) * c[idx] + sigmf(gi) * tanhf(gg);
  c[idx] = cy;
  hy[idx] = sigmf(go) * tanhf(cy);
}

// one-pass attention over an s-chunk of 128: scores + online softmax +
// partial weighted ctx sums. grid = (b=64, chunk=4)
__global__ __launch_bounds__(256) void attn_k(
    const float* __restrict__ ctx, const float* __restrict__ mask,
    const float* __restrict__ inpP,
    float* __restrict__ pm, float* __restrict__ pl, float* __restrict__ pw) {
  const int b = blockIdx.x, ch = blockIdx.y;
  const int tid = threadIdx.x;
  const int lane = tid & 63, w = tid >> 6;
  __shared__ __align__(16) float inp_s[1024];
  __shared__ __align__(16) float ctx_s[16][1024];
  __shared__ float sc_s[16];
  for (int i = tid; i < 1024; i += 256) {
    float v = 0.f;
#pragma unroll
    for (int p = 0; p < 8; ++p) v += inpP[(size_t)p * 65536 + (size_t)b * 1024 + i];
    inp_s[i] = v;
  }
  float m = -1e30f, l = 0.f;
  float pwv[4] = {0.f, 0.f, 0.f, 0.f};
  const float4* base = (const float4*)(ctx + (size_t)b * S_ * 1024 + (size_t)ch * 128 * 1024);
  for (int st = 0; st < 8; ++st) {
    __syncthreads();  // protect ctx_s reuse (and inp_s on first iter)
    const float4* src = base + (size_t)st * 4096;
    float4* dst = (float4*)ctx_s;
    for (int i = tid; i < 4096; i += 256) dst[i] = src[i];
    __syncthreads();
    for (int ss = w; ss < 16; ss += 4) {
      const float* row = ctx_s[ss];
      float p = 0.f;
#pragma unroll
      for (int i = 0; i < 16; ++i) p += row[lane + 64 * i] * inp_s[lane + 64 * i];
#pragma unroll
      for (int off = 32; off; off >>= 1) p += __shfl_down(p, off, 64);
      if (lane == 0) {
        float mk = mask[b * S_ + ch * 128 + st * 16 + ss];
        sc_s[ss] = p - (1.0f - mk) * 100000.0f;
      }
    }
    __syncthreads();
    float mloc = m;
#pragma unroll
    for (int ss = 0; ss < 16; ++ss) mloc = fmaxf(mloc, sc_s[ss]);
    float r = __expf(m - mloc);
    l *= r;
#pragma unroll
    for (int i = 0; i < 4; ++i) pwv[i] *= r;
    float e[16];
#pragma unroll
    for (int ss = 0; ss < 16; ++ss) { e[ss] = __expf(sc_s[ss] - mloc); l += e[ss]; }
#pragma unroll
    for (int i = 0; i < 4; ++i) {
      int d = tid + 256 * i;
      float a = 0.f;
#pragma unroll
      for (int ss = 0; ss < 16; ++ss) a += e[ss] * ctx_s[ss][d];
      pwv[i] += a;
    }
    m = mloc;
  }
  const int part = b * 4 + ch;
  if (tid == 0) { pm[part] = m; pl[part] = l; }
#pragma unroll
  for (int i = 0; i < 4; ++i) pw[(size_t)part * 1024 + tid + 256 * i] = pwv[i];
}

// merge softmax partials -> cat[:, :1024] = weighted_ctx ; cat[:,1024:] = inp
__global__ __launch_bounds__(256) void merge_k(
    const float* __restrict__ pm, const float* __restrict__ pl,
    const float* __restrict__ pw, const float* __restrict__ inpP,
    float* __restrict__ cat) {
  int idx = blockIdx.x * 256 + threadIdx.x;  // 64*1024
  int b = idx >> 10, d = idx & 1023;
  float m0 = pm[b * 4 + 0], m1 = pm[b * 4 + 1], m2 = pm[b * 4 + 2], m3 = pm[b * 4 + 3];
  float M = fmaxf(fmaxf(m0, m1), fmaxf(m2, m3));
  float w0 = __expf(m0 - M), w1 = __expf(m1 - M), w2 = __expf(m2 - M), w3 = __expf(m3 - M);
  float denom = w0 * pl[b * 4 + 0] + w1 * pl[b * 4 + 1] + w2 * pl[b * 4 + 2] + w3 * pl[b * 4 + 3];
  float acc = w0 * pw[(size_t)(b * 4 + 0) * 1024 + d] + w1 * pw[(size_t)(b * 4 + 1) * 1024 + d] +
              w2 * pw[(size_t)(b * 4 + 2) * 1024 + d] + w3 * pw[(size_t)(b * 4 + 3) * 1024 + d];
  cat[(size_t)b * 2048 + d] = acc / denom;
  float v = 0.f;
#pragma unroll
  for (int p = 0; p < 8; ++p) v += inpP[(size_t)p * 65536 + idx];
  cat[(size_t)b * 2048 + 1024 + d] = v;
}

// sum out-GEMM partials, tanh, write output + carry h (+ final hx/cx)
__global__ __launch_bounds__(256) void final_k(
    const float* __restrict__ hpreP, const float* __restrict__ c,
    float* __restrict__ h, float* __restrict__ out, int t) {
  int idx = blockIdx.x * 256 + threadIdx.x;  // 64*1024
  int b = idx >> 10, j = idx & 1023;
  float s = 0.f;
#pragma unroll
  for (int p = 0; p < 16; ++p) s += hpreP[(size_t)p * 65536 + idx];
  float ht = tanhf(s);
  out[((size_t)b * STEPS + t) * 1024 + j] = ht;
  h[idx] = ht;
  if (t == STEPS - 1) {
    out[(size_t)B_ * STEPS * 1024 + idx] = ht;
    out[(size_t)B_ * STEPS * 1024 + 65536 + idx] = c[idx];
  }
}

__global__ __launch_bounds__(256) void init_k(
    const float* __restrict__ hx, const float* __restrict__ cx,
    float* __restrict__ h, float* __restrict__ c) {
  int idx = blockIdx.x * 256 + threadIdx.x;  // 64*1024
  h[idx] = hx[idx];
  c[idx] = cx[idx];
}

extern "C" void kernel_launch(void* const* d_in, const int* in_sizes, int n_in,
                              void* d_out, int out_size, void* d_ws, size_t ws_size,
                              hipStream_t stream) {
  const float* hx   = (const float*)d_in[0];
  const float* cx   = (const float*)d_in[1];
  const float* ctx  = (const float*)d_in[2];
  const float* mask = (const float*)d_in[3];
  const float* Wh   = (const float*)d_in[4];
  const float* bh   = (const float*)d_in[5];
  const float* Win  = (const float*)d_in[6];
  const float* Wout = (const float*)d_in[7];
  float* out = (float*)d_out;

  float* ws = (float*)d_ws;
  float* h      = ws;                    // 64*1024
  float* c      = h + 65536;             // 64*1024
  float* hy     = c + 65536;             // 64*1024
  float* gatesP = hy + 65536;            // 4 * 64*4096
  float* inpP   = gatesP + 4 * 262144;   // 8 * 64*1024
  float* cat    = inpP + 8 * 65536;      // 64*2048
  float* hpreP  = cat + 131072;          // 16 * 64*1024
  float* pm     = hpreP + 16 * 65536;    // 256
  float* pl     = pm + 256;              // 256
  float* pw     = pl + 256;              // 4*64*1024

  init_k<<<256, 256, 0, stream>>>(hx, cx, h, c);
  for (int t = 0; t < STEPS; ++t) {
    // gates = h @ Wh^T  (N=4096, K=1024, split-K 4)
    gemm64_part<<<dim3(64, 4), 256, 0, stream>>>(h, 1024, Wh, 1024, gatesP, 4096, 256);
    cell_k<<<256, 256, 0, stream>>>(gatesP, bh, c, hy);
    // inp = hy @ W_in^T  (N=1024, K=1024, split-K 8)
    gemm64_part<<<dim3(16, 8), 256, 0, stream>>>(hy, 1024, Win, 1024, inpP, 1024, 128);
    attn_k<<<dim3(64, 4), 256, 0, stream>>>(ctx, mask, inpP, pm, pl, pw);
    merge_k<<<256, 256, 0, stream>>>(pm, pl, pw, inpP, cat);
    // hpre = cat @ W_out^T  (N=1024, K=2048, split-K 16)
    gemm64_part<<<dim3(16, 16), 256, 0, stream>>>(cat, 2048, Wout, 2048, hpreP, 1024, 128);
    final_k<<<256, 256, 0, stream>>>(hpreP, c, h, out, t);
  }
}